// Round 4
// baseline (98.441 us; speedup 1.0000x reference)
//
#include <hip/hip_runtime.h>

// SurvivalNLLLoss: hazard [T=128, B=262144] fp32, event_times [B] int,
// censored [B] int(bool). Output: scalar mean loss (fp32).
//
// Per column b: t = min(event[b], T-1), S_t = sum_{i<=t} log(1-h_i)
//   loss = -S_t + (censored ? 0 : log(1-h_t) - log(h_t))
//
// Round-4 structure: each thread owns 4 columns (float4) x 16 rows.
// ALL 16 row-loads are issued into a statically-indexed register array
// before any consumption (compiler fence between) -> 16 KB in flight per
// wave. Round 3 failed because __launch_bounds__(256,8) + partial unroll
// let the allocator shrink to 20 VGPRs = 1 load in flight = latency-bound
// at 0.5 TB/s (145us even with data L3-resident).
//
// Log2-domain accumulation (v_log_f32 native); event-term logs deferred
// out of the loop via cndmask-captured h_t. Fused deterministic last-block
// reduce (atomic counter in d_ws, zeroed by hipMemsetAsync; fixed order).

static constexpr int T_DIM  = 128;
static constexpr int NCHUNK = 8;
static constexpr int ROWS   = T_DIM / NCHUNK;   // 16
static constexpr float EPS_F = 1e-7f;
static constexpr float LN2   = 0.6931471805599453f;

__global__ __launch_bounds__(256) void surv_fused(
    const float* __restrict__ hazard,
    const int* __restrict__ event_times,
    const int* __restrict__ censored,
    float* __restrict__ partials,
    unsigned int* __restrict__ counter,
    float* __restrict__ out,
    int B, int nblocks, float inv_count)
{
    const int tc   = blockIdx.x % NCHUNK;          // T-chunk index
    const int cb   = blockIdx.x / NCHUNK;          // column-block index
    const int col0 = (cb * 256 + threadIdx.x) * 4;
    const int r0   = tc * ROWS;

    float local = 0.0f;
    if (col0 + 3 < B) {
        const int4 tt = *reinterpret_cast<const int4*>(event_times + col0);
        int t[4];
        t[0] = min(tt.x, T_DIM - 1); t[1] = min(tt.y, T_DIM - 1);
        t[2] = min(tt.z, T_DIM - 1); t[3] = min(tt.w, T_DIM - 1);

        const float* p = hazard + (size_t)r0 * (size_t)B + col0;

        // ---- issue ALL row loads first (max memory-level parallelism) ----
        float4 r[ROWS];
        #pragma unroll
        for (int i = 0; i < ROWS; ++i)
            r[i] = *reinterpret_cast<const float4*>(p + (size_t)i * (size_t)B);

        // fence: compiler may not sink the loads into the consume loop
        asm volatile("" ::: "memory");

        // ---- consume ----
        float S2[4]   = {0.0f, 0.0f, 0.0f, 0.0f};  // sum log2(1-h), i<=t
        float hsel[4] = {0.5f, 0.5f, 0.5f, 0.5f};  // clamped h at row t

        #pragma unroll
        for (int i = 0; i < ROWS; ++i) {
            const int row = r0 + i;
            const float hv[4] = {r[i].x, r[i].y, r[i].z, r[i].w};
            #pragma unroll
            for (int c = 0; c < 4; ++c) {
                const float h   = fminf(fmaxf(hv[c], EPS_F), 1.0f - EPS_F);
                const float ls2 = __log2f(1.0f - h);
                S2[c]  += (row <= t[c]) ? ls2 : 0.0f;
                hsel[c] = (row == t[c]) ? h   : hsel[c];
            }
        }

        const int4 cc = *reinterpret_cast<const int4*>(censored + col0);
        const int cens[4] = {cc.x, cc.y, cc.z, cc.w};
        #pragma unroll
        for (int c = 0; c < 4; ++c) {
            const bool has_t = (unsigned)(t[c] - r0) < (unsigned)ROWS;
            const float term = __log2f(1.0f - hsel[c]) - __log2f(hsel[c]);
            float contrib = -S2[c];
            if (has_t && (cens[c] == 0)) contrib += term;
            local += contrib;
        }
        local *= LN2;
    }

    // ---- wave (64-lane) + block reduction ----
    #pragma unroll
    for (int off = 32; off > 0; off >>= 1)
        local += __shfl_down(local, off);

    __shared__ float smem[4];
    __shared__ int   is_last;
    const int lane = threadIdx.x & 63;
    const int wid  = threadIdx.x >> 6;
    if (lane == 0) smem[wid] = local;
    __syncthreads();

    if (threadIdx.x == 0) {
        partials[blockIdx.x] = smem[0] + smem[1] + smem[2] + smem[3];
        __threadfence();                       // make partial visible device-wide
        const unsigned old = atomicAdd(counter, 1u);
        is_last = (old == (unsigned)(nblocks - 1)) ? 1 : 0;
    }
    __syncthreads();

    // ---- deterministic final reduce in the last-arriving block ----
    if (is_last) {
        __threadfence();                       // acquire all partials
        float s = 0.0f;
        for (int i = threadIdx.x; i < nblocks; i += 256)
            s += partials[i];
        #pragma unroll
        for (int off = 32; off > 0; off >>= 1)
            s += __shfl_down(s, off);
        __syncthreads();                       // smem reuse hazard
        if (lane == 0) smem[wid] = s;
        __syncthreads();
        if (threadIdx.x == 0)
            out[0] = (smem[0] + smem[1] + smem[2] + smem[3]) * inv_count;
    }
}

extern "C" void kernel_launch(void* const* d_in, const int* in_sizes, int n_in,
                              void* d_out, int out_size, void* d_ws, size_t ws_size,
                              hipStream_t stream)
{
    const float* hazard      = (const float*)d_in[0];
    const int*   event_times = (const int*)d_in[1];
    const int*   censored    = (const int*)d_in[2];
    float*       out         = (float*)d_out;

    const int B = in_sizes[1];              // 262144
    (void)n_in; (void)out_size; (void)ws_size;

    // d_ws layout: [0..4) atomic counter, [16..) per-block partials
    unsigned int* counter  = (unsigned int*)d_ws;
    float*        partials = (float*)((char*)d_ws + 16);

    const int threads = 256;
    const int cols_per_block = threads * 4;                           // 1024
    const int col_blocks = (B + cols_per_block - 1) / cols_per_block; // 256
    const int nblocks = col_blocks * NCHUNK;                          // 2048

    hipMemsetAsync(counter, 0, sizeof(unsigned int), stream);

    surv_fused<<<nblocks, threads, 0, stream>>>(hazard, event_times, censored,
                                                partials, counter, out,
                                                B, nblocks, 1.0f / (float)B);
}

// Round 5
// 29.962 us; speedup vs baseline: 3.2856x; 3.2856x over previous
//
#include <hip/hip_runtime.h>

// SurvivalNLLLoss: hazard [T=128, B=262144] fp32, event_times [B] int,
// censored [B] int(bool). Output: scalar mean loss (fp32).
//
// Per column b: t = min(event[b], T-1), S_t = sum_{i<=t} log(1-h_i)
//   loss = -S_t + (censored ? 0 : log(1-h_t) - log(h_t))
//
// Round-5: revert to the round-2 skeleton (two kernels, NO device-scope
// fence: rounds 3/4's fused last-block reduce used __threadfence(), which
// on gfx950 emits buffer_wbl2 (whole-L2 writeback) per block -> ~100us of
// serialized L2 flushes; warm replays were 143us with only 0.13MB of HBM
// traffic = pure serialization, not BW).
// Single upgrade vs round 2: float4 loads (4 cols/thread) + unroll 8
// -> ~8KB in flight per wave, half the load/addr instructions per byte.
// Log2-domain accumulate; event-term logs deferred out of the loop.

static constexpr int T_DIM  = 128;
static constexpr int NCHUNK = 4;
static constexpr int ROWS   = T_DIM / NCHUNK;   // 32
static constexpr float EPS_F = 1e-7f;
static constexpr float LN2   = 0.6931471805599453f;

// ---------------- pass 1: per-block partial sums -----------------------------
__global__ __launch_bounds__(256) void surv_partial(
    const float* __restrict__ hazard,
    const int* __restrict__ event_times,
    const int* __restrict__ censored,
    float* __restrict__ partials, int B)
{
    const int tc   = blockIdx.x % NCHUNK;          // T-chunk index
    const int cb   = blockIdx.x / NCHUNK;          // column-block index
    const int col0 = (cb * 256 + threadIdx.x) * 4;
    const int r0   = tc * ROWS;

    float local = 0.0f;
    if (col0 + 3 < B) {
        const int4 tt = *reinterpret_cast<const int4*>(event_times + col0);
        int t[4];
        t[0] = min(tt.x, T_DIM - 1); t[1] = min(tt.y, T_DIM - 1);
        t[2] = min(tt.z, T_DIM - 1); t[3] = min(tt.w, T_DIM - 1);

        float S2[4]   = {0.0f, 0.0f, 0.0f, 0.0f};  // sum log2(1-h), i<=t
        float hsel[4] = {0.5f, 0.5f, 0.5f, 0.5f};  // clamped h at row t

        const float* p = hazard + (size_t)r0 * (size_t)B + col0;

        #pragma unroll 8
        for (int i = 0; i < ROWS; ++i) {
            const float4 h4 = *reinterpret_cast<const float4*>(
                p + (size_t)i * (size_t)B);
            const int row = r0 + i;
            const float hv[4] = {h4.x, h4.y, h4.z, h4.w};
            #pragma unroll
            for (int c = 0; c < 4; ++c) {
                const float h   = fminf(fmaxf(hv[c], EPS_F), 1.0f - EPS_F);
                const float ls2 = __log2f(1.0f - h);
                S2[c]  += (row <= t[c]) ? ls2 : 0.0f;
                hsel[c] = (row == t[c]) ? h   : hsel[c];
            }
        }

        const int4 cc = *reinterpret_cast<const int4*>(censored + col0);
        const int cens[4] = {cc.x, cc.y, cc.z, cc.w};
        #pragma unroll
        for (int c = 0; c < 4; ++c) {
            const bool has_t = (unsigned)(t[c] - r0) < (unsigned)ROWS;
            const float term = __log2f(1.0f - hsel[c]) - __log2f(hsel[c]);
            float contrib = -S2[c];
            if (has_t && (cens[c] == 0)) contrib += term;
            local += contrib;
        }
        local *= LN2;
    }

    // ---- wave (64-lane) + block reduction ----
    #pragma unroll
    for (int off = 32; off > 0; off >>= 1)
        local += __shfl_down(local, off);

    __shared__ float smem[4];
    const int lane = threadIdx.x & 63;
    const int wid  = threadIdx.x >> 6;
    if (lane == 0) smem[wid] = local;
    __syncthreads();
    if (threadIdx.x == 0)
        partials[blockIdx.x] = smem[0] + smem[1] + smem[2] + smem[3];
}

// ---------------- pass 2: deterministic final reduce -------------------------
__global__ __launch_bounds__(256) void surv_final(
    const float* __restrict__ partials, int n,
    float* __restrict__ out, float inv_count)
{
    float local = 0.0f;
    for (int i = threadIdx.x; i < n; i += 256)
        local += partials[i];

    #pragma unroll
    for (int off = 32; off > 0; off >>= 1)
        local += __shfl_down(local, off);

    __shared__ float smem[4];
    const int lane = threadIdx.x & 63;
    const int wid  = threadIdx.x >> 6;
    if (lane == 0) smem[wid] = local;
    __syncthreads();
    if (threadIdx.x == 0)
        out[0] = (smem[0] + smem[1] + smem[2] + smem[3]) * inv_count;
}

extern "C" void kernel_launch(void* const* d_in, const int* in_sizes, int n_in,
                              void* d_out, int out_size, void* d_ws, size_t ws_size,
                              hipStream_t stream)
{
    const float* hazard      = (const float*)d_in[0];
    const int*   event_times = (const int*)d_in[1];
    const int*   censored    = (const int*)d_in[2];
    float*       out         = (float*)d_out;

    const int B = in_sizes[1];              // 262144
    (void)n_in; (void)out_size; (void)ws_size;

    float* partials = (float*)d_ws;

    const int threads = 256;
    const int cols_per_block = threads * 4;                           // 1024
    const int col_blocks = (B + cols_per_block - 1) / cols_per_block; // 256
    const int nblocks = col_blocks * NCHUNK;                          // 1024

    surv_partial<<<nblocks, threads, 0, stream>>>(hazard, event_times, censored,
                                                  partials, B);
    surv_final<<<1, threads, 0, stream>>>(partials, nblocks, out, 1.0f / (float)B);
}